// Round 4
// baseline (107.944 us; speedup 1.0000x reference)
//
#include <hip/hip_runtime.h>
#include <hip/hip_bf16.h>
#include <math.h>

#define NSEQ 512
#define EMB 256

// order-preserving float<->uint encoding for atomic max
__device__ __forceinline__ unsigned fenc(float f) {
    unsigned u = __float_as_uint(f);
    return (u & 0x80000000u) ? ~u : (u | 0x80000000u);
}
__device__ __forceinline__ float fdec(unsigned e) {
    unsigned u = (e & 0x80000000u) ? (e ^ 0x80000000u) : ~e;
    return __uint_as_float(u);
}

__device__ __forceinline__ float dot4acc(float acc, float4 a, float4 b) {
    acc = fmaf(a.x, b.x, acc);
    acc = fmaf(a.y, b.y, acc);
    acc = fmaf(a.z, b.z, acc);
    acc = fmaf(a.w, b.w, acc);
    return acc;
}

// K1: C[1024][768] = X @ [Wq-Wr; Wk+Wr; Wv]^T (+bias for Q',K',V), and
// P = X@Wr^T reduced to per-(batch,chan) MAX only (min cancels in softmax).
// grid (16 m-tiles, 16 n-tiles) x 256; 64x64 tile, 4x4/thread, reg-dbuf over K.
__global__ __launch_bounds__(256, 2) void k_gemm_proj(
    const float* __restrict__ X,
    const float* __restrict__ Wq, const float* __restrict__ Wk,
    const float* __restrict__ Wv, const float* __restrict__ Wr,
    const float* __restrict__ bq, const float* __restrict__ bk,
    const float* __restrict__ bv,
    float* __restrict__ C,
    unsigned* __restrict__ maxEnc)
{
    __shared__ __align__(16) float As[64][68];
    __shared__ __align__(16) float Bs[64][68];
    const int t = threadIdx.x;
    const int tx = t & 15, ty = t >> 4;
    const int m0 = blockIdx.x * 64;
    const int n0 = blockIdx.y * 64;
    const int seg = blockIdx.y >> 2;          // 0:Q' 1:K' 2:V 3:P
    const int wbase = (blockIdx.y & 3) * 64;  // row offset within the 256-row W

    float4 aR[4], bR[4];

    auto loadfrags = [&](int k0) {
        #pragma unroll
        for (int p = 0; p < 4; ++p) {
            int row = p * 16 + ty;
            aR[p] = ((const float4*)(X + (size_t)(m0 + row) * 256 + k0))[tx];
            size_t woff = (size_t)(wbase + row) * 256 + k0;
            if (seg == 0) {
                float4 a = ((const float4*)(Wq + woff))[tx];
                float4 r = ((const float4*)(Wr + woff))[tx];
                bR[p] = make_float4(a.x - r.x, a.y - r.y, a.z - r.z, a.w - r.w);
            } else if (seg == 1) {
                float4 a = ((const float4*)(Wk + woff))[tx];
                float4 r = ((const float4*)(Wr + woff))[tx];
                bR[p] = make_float4(a.x + r.x, a.y + r.y, a.z + r.z, a.w + r.w);
            } else if (seg == 2) {
                bR[p] = ((const float4*)(Wv + woff))[tx];
            } else {
                bR[p] = ((const float4*)(Wr + woff))[tx];
            }
        }
    };

    float acc[4][4] = {{0.f}};
    loadfrags(0);

    #pragma unroll
    for (int kc = 0; kc < 4; ++kc) {
        __syncthreads();
        #pragma unroll
        for (int p = 0; p < 4; ++p) {
            int row = p * 16 + ty;
            int sr = row ^ ((tx & 3) << 2);
            As[tx * 4 + 0][sr] = aR[p].x; As[tx * 4 + 1][sr] = aR[p].y;
            As[tx * 4 + 2][sr] = aR[p].z; As[tx * 4 + 3][sr] = aR[p].w;
            Bs[tx * 4 + 0][sr] = bR[p].x; Bs[tx * 4 + 1][sr] = bR[p].y;
            Bs[tx * 4 + 2][sr] = bR[p].z; Bs[tx * 4 + 3][sr] = bR[p].w;
        }
        __syncthreads();
        if (kc < 3) loadfrags((kc + 1) * 64);   // overlap with compute below
        #pragma unroll 16
        for (int k = 0; k < 64; ++k) {
            int s = ((k >> 2) & 3) << 2;
            float4 a4 = *(const float4*)&As[k][(ty * 4) ^ s];
            float4 b4 = *(const float4*)&Bs[k][(tx * 4) ^ s];
            acc[0][0] = fmaf(a4.x, b4.x, acc[0][0]);
            acc[0][1] = fmaf(a4.x, b4.y, acc[0][1]);
            acc[0][2] = fmaf(a4.x, b4.z, acc[0][2]);
            acc[0][3] = fmaf(a4.x, b4.w, acc[0][3]);
            acc[1][0] = fmaf(a4.y, b4.x, acc[1][0]);
            acc[1][1] = fmaf(a4.y, b4.y, acc[1][1]);
            acc[1][2] = fmaf(a4.y, b4.z, acc[1][2]);
            acc[1][3] = fmaf(a4.y, b4.w, acc[1][3]);
            acc[2][0] = fmaf(a4.z, b4.x, acc[2][0]);
            acc[2][1] = fmaf(a4.z, b4.y, acc[2][1]);
            acc[2][2] = fmaf(a4.z, b4.z, acc[2][2]);
            acc[2][3] = fmaf(a4.z, b4.w, acc[2][3]);
            acc[3][0] = fmaf(a4.w, b4.x, acc[3][0]);
            acc[3][1] = fmaf(a4.w, b4.y, acc[3][1]);
            acc[3][2] = fmaf(a4.w, b4.z, acc[3][2]);
            acc[3][3] = fmaf(a4.w, b4.w, acc[3][3]);
        }
    }

    if (seg < 3) {
        const float* bias = (seg == 0) ? bq : ((seg == 1) ? bk : bv);
        float4 bf = ((const float4*)(bias + (n0 & 255)))[tx];
        #pragma unroll
        for (int r = 0; r < 4; ++r) {
            float4 o = make_float4(acc[r][0] + bf.x, acc[r][1] + bf.y,
                                   acc[r][2] + bf.z, acc[r][3] + bf.w);
            *((float4*)(C + (size_t)(m0 + ty * 4 + r) * 768 + n0 + tx * 4)) = o;
        }
    } else {
        __syncthreads();
        float* redmax = &Bs[0][0];
        #pragma unroll
        for (int c = 0; c < 4; ++c) {
            float mx = fmaxf(fmaxf(acc[0][c], acc[1][c]), fmaxf(acc[2][c], acc[3][c]));
            redmax[ty * 64 + tx * 4 + c] = mx;
        }
        __syncthreads();
        if (t < 64) {
            float mx = redmax[t];
            #pragma unroll
            for (int g = 1; g < 16; ++g)
                mx = fmaxf(mx, redmax[g * 64 + t]);
            const int b = m0 >> 9;
            const int c = (n0 & 255) + t;
            atomicMax(&maxEnc[b * 256 + c], fenc(mx));
        }
    }
}

// K2: attention. grid (32 q-tiles, 8 heads, 2 batches) x 256.
// K-side bias cancels in softmax, so K/V staging is a pure copy.
// Reg-dbuf prefetch across the barrier; NO occupancy clause (spill-free).
__global__ __launch_bounds__(256) void k_attn(
    const float* __restrict__ C,
    const unsigned* __restrict__ maxEnc,
    const float* __restrict__ br, float* __restrict__ attnw)
{
    __shared__ __align__(16) float ks[128][36];
    __shared__ __align__(16) float vs[128][36];
    __shared__ __align__(16) float qadd[32];

    const int t = threadIdx.x;
    const int q0 = blockIdx.x * 16;
    const int h  = blockIdx.y;
    const int b  = blockIdx.z;
    const int e0 = h * 32;
    const int tq = t >> 5, tk = t & 31;
    const float scale = 0.17677669529663687f;  // 1/sqrt(32)

    if (t < 32)
        qadd[t] = fdec(maxEnc[b * 256 + e0 + t]) + br[e0 + t];

    float4 kR[4], vR[4];
    auto loadKV = [&](int kc) {
        #pragma unroll
        for (int i = 0; i < 4; ++i) {
            int f4 = t + 256 * i;
            int row = f4 >> 3, c4 = f4 & 7;
            size_t m = (size_t)(b * NSEQ + kc * 128 + row);
            kR[i] = ((const float4*)(C + m * 768 + 256 + e0))[c4];
            vR[i] = ((const float4*)(C + m * 768 + 512 + e0))[c4];
        }
    };
    loadKV(0);
    __syncthreads();   // qadd ready

    // Qr = C_q + (maxP + br)
    float4 qreg[2][8];
    #pragma unroll
    for (int r = 0; r < 2; ++r) {
        size_t m = (size_t)(b * NSEQ + q0 + 2 * tq + r);
        const float4* Crow = (const float4*)(C + m * 768 + e0);
        #pragma unroll
        for (int i = 0; i < 8; ++i) {
            float4 qv = Crow[i];
            float4 ad = ((const float4*)qadd)[i];
            qreg[r][i] = make_float4(qv.x + ad.x, qv.y + ad.y, qv.z + ad.z, qv.w + ad.w);
        }
    }

    float m_run[2] = {-1e30f, -1e30f};
    float l_run[2] = {0.f, 0.f};
    float4 pacc[2][8];
    #pragma unroll
    for (int r = 0; r < 2; ++r)
        #pragma unroll
        for (int i = 0; i < 8; ++i)
            pacc[r][i] = make_float4(0.f, 0.f, 0.f, 0.f);

    #pragma unroll
    for (int kc = 0; kc < 4; ++kc) {
        __syncthreads();
        #pragma unroll
        for (int i = 0; i < 4; ++i) {
            int f4 = t + 256 * i;
            int row = f4 >> 3, c4 = f4 & 7;
            ((float4*)&ks[row][0])[c4] = kR[i];
            ((float4*)&vs[row][0])[c4] = vR[i];
        }
        __syncthreads();
        if (kc < 3) loadKV(kc + 1);   // prefetch next chunk across compute

        float p[2][4];
        float mloc[2] = {-1e30f, -1e30f};
        #pragma unroll
        for (int j = 0; j < 4; ++j) {
            int kj = tk + 32 * j;
            const float4* krow = (const float4*)&ks[kj][0];
            float s0 = 0.f, s1 = 0.f;
            #pragma unroll
            for (int i = 0; i < 8; ++i) {
                float4 kf = krow[i];
                s0 = dot4acc(s0, qreg[0][i], kf);
                s1 = dot4acc(s1, qreg[1][i], kf);
            }
            p[0][j] = s0 * scale;
            p[1][j] = s1 * scale;
            mloc[0] = fmaxf(mloc[0], p[0][j]);
            mloc[1] = fmaxf(mloc[1], p[1][j]);
        }
        #pragma unroll
        for (int off = 1; off < 32; off <<= 1) {
            mloc[0] = fmaxf(mloc[0], __shfl_xor(mloc[0], off));
            mloc[1] = fmaxf(mloc[1], __shfl_xor(mloc[1], off));
        }
        #pragma unroll
        for (int r = 0; r < 2; ++r) {
            float m_new = fmaxf(m_run[r], mloc[r]);
            float sc = __expf(m_run[r] - m_new);
            m_run[r] = m_new;
            float ls = 0.f;
            #pragma unroll
            for (int j = 0; j < 4; ++j) {
                p[r][j] = __expf(p[r][j] - m_new);
                ls += p[r][j];
            }
            #pragma unroll
            for (int off = 1; off < 32; off <<= 1) ls += __shfl_xor(ls, off);
            l_run[r] = l_run[r] * sc + ls;
            #pragma unroll
            for (int i = 0; i < 8; ++i) {
                pacc[r][i].x *= sc; pacc[r][i].y *= sc;
                pacc[r][i].z *= sc; pacc[r][i].w *= sc;
            }
        }
        #pragma unroll
        for (int j = 0; j < 4; ++j) {
            int kj = tk + 32 * j;
            const float4* vrow = (const float4*)&vs[kj][0];
            float p0 = p[0][j], p1 = p[1][j];
            #pragma unroll
            for (int i = 0; i < 8; ++i) {
                float4 vf = vrow[i];
                pacc[0][i].x = fmaf(p0, vf.x, pacc[0][i].x);
                pacc[0][i].y = fmaf(p0, vf.y, pacc[0][i].y);
                pacc[0][i].z = fmaf(p0, vf.z, pacc[0][i].z);
                pacc[0][i].w = fmaf(p0, vf.w, pacc[0][i].w);
                pacc[1][i].x = fmaf(p1, vf.x, pacc[1][i].x);
                pacc[1][i].y = fmaf(p1, vf.y, pacc[1][i].y);
                pacc[1][i].z = fmaf(p1, vf.z, pacc[1][i].z);
                pacc[1][i].w = fmaf(p1, vf.w, pacc[1][i].w);
            }
        }
    }

    // butterfly-sum across the 32 tk lanes
    #pragma unroll
    for (int r = 0; r < 2; ++r) {
        #pragma unroll
        for (int i = 0; i < 8; ++i) {
            float4 v = pacc[r][i];
            #pragma unroll
            for (int off = 1; off < 32; off <<= 1) {
                v.x += __shfl_xor(v.x, off);
                v.y += __shfl_xor(v.y, off);
                v.z += __shfl_xor(v.z, off);
                v.w += __shfl_xor(v.w, off);
            }
            pacc[r][i] = v;
        }
    }

    // lane tk writes channel tk (static-index select, no scratch)
    #pragma unroll
    for (int r = 0; r < 2; ++r) {
        float val = 0.f;
        #pragma unroll
        for (int i = 0; i < 8; ++i) {
            float4 v = pacc[r][i];
            int cc = tk & 3;
            float comp = (cc == 0) ? v.x : ((cc == 1) ? v.y : ((cc == 2) ? v.z : v.w));
            if ((tk >> 2) == i) val = comp;
        }
        size_t m = (size_t)(b * NSEQ + q0 + 2 * tq + r);
        attnw[m * 256 + e0 + tk] = val / l_run[r];
    }
}

// K3: split-K out-projection partials. grid (16 m, 4 n, 4 ksplit) x 256.
__global__ __launch_bounds__(256, 2) void k_ogemm(
    const float* __restrict__ A, const float* __restrict__ Wo,
    float* __restrict__ yPart)
{
    __shared__ __align__(16) float As[64][68];
    __shared__ __align__(16) float Bs[64][68];
    const int t = threadIdx.x;
    const int tx = t & 15, ty = t >> 4;
    const int m0 = blockIdx.x * 64;
    const int n0 = blockIdx.y * 64;
    const int k0 = blockIdx.z * 64;

    #pragma unroll
    for (int p = 0; p < 4; ++p) {
        int row = p * 16 + ty;
        float4 a = ((const float4*)(A  + (size_t)(m0 + row) * 256 + k0))[tx];
        float4 b = ((const float4*)(Wo + (size_t)(n0 + row) * 256 + k0))[tx];
        int sr = row ^ ((tx & 3) << 2);
        As[tx * 4 + 0][sr] = a.x; As[tx * 4 + 1][sr] = a.y;
        As[tx * 4 + 2][sr] = a.z; As[tx * 4 + 3][sr] = a.w;
        Bs[tx * 4 + 0][sr] = b.x; Bs[tx * 4 + 1][sr] = b.y;
        Bs[tx * 4 + 2][sr] = b.z; Bs[tx * 4 + 3][sr] = b.w;
    }
    __syncthreads();

    float acc[4][4] = {{0.f}};
    #pragma unroll 16
    for (int k = 0; k < 64; ++k) {
        int s = ((k >> 2) & 3) << 2;
        float4 a4 = *(const float4*)&As[k][(ty * 4) ^ s];
        float4 b4 = *(const float4*)&Bs[k][(tx * 4) ^ s];
        acc[0][0] = fmaf(a4.x, b4.x, acc[0][0]);
        acc[0][1] = fmaf(a4.x, b4.y, acc[0][1]);
        acc[0][2] = fmaf(a4.x, b4.z, acc[0][2]);
        acc[0][3] = fmaf(a4.x, b4.w, acc[0][3]);
        acc[1][0] = fmaf(a4.y, b4.x, acc[1][0]);
        acc[1][1] = fmaf(a4.y, b4.y, acc[1][1]);
        acc[1][2] = fmaf(a4.y, b4.z, acc[1][2]);
        acc[1][3] = fmaf(a4.y, b4.w, acc[1][3]);
        acc[2][0] = fmaf(a4.z, b4.x, acc[2][0]);
        acc[2][1] = fmaf(a4.z, b4.y, acc[2][1]);
        acc[2][2] = fmaf(a4.z, b4.z, acc[2][2]);
        acc[2][3] = fmaf(a4.z, b4.w, acc[2][3]);
        acc[3][0] = fmaf(a4.w, b4.x, acc[3][0]);
        acc[3][1] = fmaf(a4.w, b4.y, acc[3][1]);
        acc[3][2] = fmaf(a4.w, b4.z, acc[3][2]);
        acc[3][3] = fmaf(a4.w, b4.w, acc[3][3]);
    }

    float* dst = yPart + (size_t)blockIdx.z * (1024 * 256);
    #pragma unroll
    for (int r = 0; r < 4; ++r) {
        float4 o = make_float4(acc[r][0], acc[r][1], acc[r][2], acc[r][3]);
        *((float4*)(dst + (size_t)(m0 + ty * 4 + r) * 256 + n0 + tx * 4)) = o;
    }
}

// K4: y = x + bo + sum(yPart) ; LN1 ; LN2. grid 256 x 256; 4 rows/block.
__global__ __launch_bounds__(256) void k_lnorm(
    const float* __restrict__ yP, const float* __restrict__ x,
    const float* __restrict__ bo,
    const float* __restrict__ g1, const float* __restrict__ b1,
    const float* __restrict__ g2, const float* __restrict__ b2,
    float* __restrict__ out)
{
    __shared__ float red[4][4][2];
    const int t = threadIdx.x;
    const int r0 = blockIdx.x * 4;
    const int c = t;
    const int wid = t >> 6, lane = t & 63;

    float y[4];
    #pragma unroll
    for (int r = 0; r < 4; ++r) {
        size_t off = (size_t)(r0 + r) * 256 + c;
        y[r] = x[off] + bo[c] + yP[off] + yP[262144 + off]
             + yP[524288 + off] + yP[786432 + off];
    }

    // LN1
    #pragma unroll
    for (int r = 0; r < 4; ++r) {
        float s = y[r], s2 = y[r] * y[r];
        #pragma unroll
        for (int off = 32; off > 0; off >>= 1) {
            s  += __shfl_xor(s, off);
            s2 += __shfl_xor(s2, off);
        }
        if (lane == 0) { red[wid][r][0] = s; red[wid][r][1] = s2; }
    }
    __syncthreads();
    float t1[4];
    #pragma unroll
    for (int r = 0; r < 4; ++r) {
        float s  = red[0][r][0] + red[1][r][0] + red[2][r][0] + red[3][r][0];
        float s2 = red[0][r][1] + red[1][r][1] + red[2][r][1] + red[3][r][1];
        float mu = s * (1.f / 256.f);
        float var = s2 * (1.f / 256.f) - mu * mu;
        float rs = rsqrtf(var + 1e-5f);
        t1[r] = (y[r] - mu) * rs * g1[c] + b1[c];
    }
    __syncthreads();

    // LN2
    #pragma unroll
    for (int r = 0; r < 4; ++r) {
        float s = t1[r], s2 = t1[r] * t1[r];
        #pragma unroll
        for (int off = 32; off > 0; off >>= 1) {
            s  += __shfl_xor(s, off);
            s2 += __shfl_xor(s2, off);
        }
        if (lane == 0) { red[wid][r][0] = s; red[wid][r][1] = s2; }
    }
    __syncthreads();
    #pragma unroll
    for (int r = 0; r < 4; ++r) {
        float s  = red[0][r][0] + red[1][r][0] + red[2][r][0] + red[3][r][0];
        float s2 = red[0][r][1] + red[1][r][1] + red[2][r][1] + red[3][r][1];
        float mu = s * (1.f / 256.f);
        float var = s2 * (1.f / 256.f) - mu * mu;
        float rs = rsqrtf(var + 1e-5f);
        out[(size_t)(r0 + r) * 256 + c] = (t1[r] - mu) * rs * g2[c] + b2[c];
    }
}

extern "C" void kernel_launch(void* const* d_in, const int* in_sizes, int n_in,
                              void* d_out, int out_size, void* d_ws, size_t ws_size,
                              hipStream_t stream)
{
    const float* x  = (const float*)d_in[0];
    const float* Wq = (const float*)d_in[1];
    const float* bq = (const float*)d_in[2];
    const float* Wk = (const float*)d_in[3];
    const float* bk = (const float*)d_in[4];
    const float* Wv = (const float*)d_in[5];
    const float* bv = (const float*)d_in[6];
    const float* Wr = (const float*)d_in[7];
    const float* br = (const float*)d_in[8];
    const float* Wo = (const float*)d_in[9];
    const float* bo = (const float*)d_in[10];
    const float* g1 = (const float*)d_in[11];
    const float* b1 = (const float*)d_in[12];
    const float* g2 = (const float*)d_in[13];
    const float* b2 = (const float*)d_in[14];
    float* out = (float*)d_out;
    float* ws = (float*)d_ws;

    float* C     = ws;                       // 1024*768
    float* attnw = ws + 786432;              // 1024*256
    float* yP    = ws + 1048576;             // 4 * 1024*256
    unsigned* maxEnc = (unsigned*)(ws + 2097152);  // 512

    hipMemsetAsync(maxEnc, 0x00, 512 * sizeof(unsigned), stream);

    k_gemm_proj<<<dim3(16, 16), 256, 0, stream>>>(x, Wq, Wk, Wv, Wr, bq, bk, bv,
                                                  C, maxEnc);
    k_attn<<<dim3(32, 8, 2), 256, 0, stream>>>(C, maxEnc, br, attnw);
    k_ogemm<<<dim3(16, 4, 4), 256, 0, stream>>>(attnw, Wo, yP);
    k_lnorm<<<256, 256, 0, stream>>>(yP, x, bo, g1, b1, g2, b2, out);
}

// Round 5
// 67.583 us; speedup vs baseline: 1.5972x; 1.5972x over previous
//
#include <hip/hip_runtime.h>
#include <hip/hip_bf16.h>
#include <math.h>

#define NSEQ 512
#define EMB 256

// order-preserving float<->uint encoding for atomic max
__device__ __forceinline__ unsigned fenc(float f) {
    unsigned u = __float_as_uint(f);
    return (u & 0x80000000u) ? ~u : (u | 0x80000000u);
}
__device__ __forceinline__ float fdec(unsigned e) {
    unsigned u = (e & 0x80000000u) ? (e ^ 0x80000000u) : ~e;
    return __uint_as_float(u);
}

__device__ __forceinline__ float dot4acc(float acc, float4 a, float4 b) {
    acc = fmaf(a.x, b.x, acc);
    acc = fmaf(a.y, b.y, acc);
    acc = fmaf(a.z, b.z, acc);
    acc = fmaf(a.w, b.w, acc);
    return acc;
}

// K1: C[1024][768] = X @ [Wq-Wr; Wk+Wr; Wv]^T (+bias for Q',K',V), and
// P = X@Wr^T reduced to per-(batch,chan) MAX only (min cancels in softmax).
// grid (16 m-tiles, 16 n-tiles) x 256; 64x64 tile, 4x4/thread, reg-dbuf over K.
__global__ __launch_bounds__(256, 2) void k_gemm_proj(
    const float* __restrict__ X,
    const float* __restrict__ Wq, const float* __restrict__ Wk,
    const float* __restrict__ Wv, const float* __restrict__ Wr,
    const float* __restrict__ bq, const float* __restrict__ bk,
    const float* __restrict__ bv,
    float* __restrict__ C,
    unsigned* __restrict__ maxEnc)
{
    __shared__ __align__(16) float As[64][68];
    __shared__ __align__(16) float Bs[64][68];
    const int t = threadIdx.x;
    const int tx = t & 15, ty = t >> 4;
    const int m0 = blockIdx.x * 64;
    const int n0 = blockIdx.y * 64;
    const int seg = blockIdx.y >> 2;          // 0:Q' 1:K' 2:V 3:P
    const int wbase = (blockIdx.y & 3) * 64;  // row offset within the 256-row W

    float4 aR[4], bR[4];

    auto loadfrags = [&](int k0) {
        #pragma unroll
        for (int p = 0; p < 4; ++p) {
            int row = p * 16 + ty;
            aR[p] = ((const float4*)(X + (size_t)(m0 + row) * 256 + k0))[tx];
            size_t woff = (size_t)(wbase + row) * 256 + k0;
            if (seg == 0) {
                float4 a = ((const float4*)(Wq + woff))[tx];
                float4 r = ((const float4*)(Wr + woff))[tx];
                bR[p] = make_float4(a.x - r.x, a.y - r.y, a.z - r.z, a.w - r.w);
            } else if (seg == 1) {
                float4 a = ((const float4*)(Wk + woff))[tx];
                float4 r = ((const float4*)(Wr + woff))[tx];
                bR[p] = make_float4(a.x + r.x, a.y + r.y, a.z + r.z, a.w + r.w);
            } else if (seg == 2) {
                bR[p] = ((const float4*)(Wv + woff))[tx];
            } else {
                bR[p] = ((const float4*)(Wr + woff))[tx];
            }
        }
    };

    float acc[4][4] = {{0.f}};
    loadfrags(0);

    #pragma unroll
    for (int kc = 0; kc < 4; ++kc) {
        __syncthreads();
        #pragma unroll
        for (int p = 0; p < 4; ++p) {
            int row = p * 16 + ty;
            int sr = row ^ ((tx & 3) << 2);
            As[tx * 4 + 0][sr] = aR[p].x; As[tx * 4 + 1][sr] = aR[p].y;
            As[tx * 4 + 2][sr] = aR[p].z; As[tx * 4 + 3][sr] = aR[p].w;
            Bs[tx * 4 + 0][sr] = bR[p].x; Bs[tx * 4 + 1][sr] = bR[p].y;
            Bs[tx * 4 + 2][sr] = bR[p].z; Bs[tx * 4 + 3][sr] = bR[p].w;
        }
        __syncthreads();
        if (kc < 3) loadfrags((kc + 1) * 64);   // overlap with compute below
        #pragma unroll 16
        for (int k = 0; k < 64; ++k) {
            int s = ((k >> 2) & 3) << 2;
            float4 a4 = *(const float4*)&As[k][(ty * 4) ^ s];
            float4 b4 = *(const float4*)&Bs[k][(tx * 4) ^ s];
            acc[0][0] = fmaf(a4.x, b4.x, acc[0][0]);
            acc[0][1] = fmaf(a4.x, b4.y, acc[0][1]);
            acc[0][2] = fmaf(a4.x, b4.z, acc[0][2]);
            acc[0][3] = fmaf(a4.x, b4.w, acc[0][3]);
            acc[1][0] = fmaf(a4.y, b4.x, acc[1][0]);
            acc[1][1] = fmaf(a4.y, b4.y, acc[1][1]);
            acc[1][2] = fmaf(a4.y, b4.z, acc[1][2]);
            acc[1][3] = fmaf(a4.y, b4.w, acc[1][3]);
            acc[2][0] = fmaf(a4.z, b4.x, acc[2][0]);
            acc[2][1] = fmaf(a4.z, b4.y, acc[2][1]);
            acc[2][2] = fmaf(a4.z, b4.z, acc[2][2]);
            acc[2][3] = fmaf(a4.z, b4.w, acc[2][3]);
            acc[3][0] = fmaf(a4.w, b4.x, acc[3][0]);
            acc[3][1] = fmaf(a4.w, b4.y, acc[3][1]);
            acc[3][2] = fmaf(a4.w, b4.z, acc[3][2]);
            acc[3][3] = fmaf(a4.w, b4.w, acc[3][3]);
        }
    }

    if (seg < 3) {
        const float* bias = (seg == 0) ? bq : ((seg == 1) ? bk : bv);
        float4 bf = ((const float4*)(bias + (n0 & 255)))[tx];
        #pragma unroll
        for (int r = 0; r < 4; ++r) {
            float4 o = make_float4(acc[r][0] + bf.x, acc[r][1] + bf.y,
                                   acc[r][2] + bf.z, acc[r][3] + bf.w);
            *((float4*)(C + (size_t)(m0 + ty * 4 + r) * 768 + n0 + tx * 4)) = o;
        }
    } else {
        __syncthreads();
        float* redmax = &Bs[0][0];
        #pragma unroll
        for (int c = 0; c < 4; ++c) {
            float mx = fmaxf(fmaxf(acc[0][c], acc[1][c]), fmaxf(acc[2][c], acc[3][c]));
            redmax[ty * 64 + tx * 4 + c] = mx;
        }
        __syncthreads();
        if (t < 64) {
            float mx = redmax[t];
            #pragma unroll
            for (int g = 1; g < 16; ++g)
                mx = fmaxf(mx, redmax[g * 64 + t]);
            const int b = m0 >> 9;
            const int c = (n0 & 255) + t;
            atomicMax(&maxEnc[b * 256 + c], fenc(mx));
        }
    }
}

// K2: attention. grid (32 q-tiles of 16 rows, 8 heads, 2 batches) x 256.
// Round-2 proven structure: direct global->LDS staging, NO register prefetch
// (reg-dbuf spilled in r3/r4: qreg64+pacc64+kRvR32 > allocator budget).
// K-side softmax bias cancels -> staging is a pure copy; only maxEnc needed.
__global__ __launch_bounds__(256) void k_attn(
    const float* __restrict__ C,
    const unsigned* __restrict__ maxEnc,
    const float* __restrict__ br, float* __restrict__ attnw)
{
    __shared__ __align__(16) float ks[128][36];
    __shared__ __align__(16) float vs[128][36];
    __shared__ __align__(16) float qadd[32];

    const int t = threadIdx.x;
    const int q0 = blockIdx.x * 16;
    const int h  = blockIdx.y;
    const int b  = blockIdx.z;
    const int e0 = h * 32;
    const int tq = t >> 5, tk = t & 31;
    const float scale = 0.17677669529663687f;  // 1/sqrt(32)

    if (t < 32)
        qadd[t] = fdec(maxEnc[b * 256 + e0 + t]) + br[e0 + t];
    __syncthreads();

    // Qr = C_q + (maxP + br)
    float4 qreg[2][8];
    #pragma unroll
    for (int r = 0; r < 2; ++r) {
        size_t m = (size_t)(b * NSEQ + q0 + 2 * tq + r);
        const float4* Crow = (const float4*)(C + m * 768 + e0);
        #pragma unroll
        for (int i = 0; i < 8; ++i) {
            float4 qv = Crow[i];
            float4 ad = ((const float4*)qadd)[i];
            qreg[r][i] = make_float4(qv.x + ad.x, qv.y + ad.y, qv.z + ad.z, qv.w + ad.w);
        }
    }

    float m_run[2] = {-1e30f, -1e30f};
    float l_run[2] = {0.f, 0.f};
    float4 pacc[2][8];
    #pragma unroll
    for (int r = 0; r < 2; ++r)
        #pragma unroll
        for (int i = 0; i < 8; ++i)
            pacc[r][i] = make_float4(0.f, 0.f, 0.f, 0.f);

    for (int kc = 0; kc < 4; ++kc) {
        __syncthreads();
        // stage K,V (pure copy)
        #pragma unroll
        for (int i = 0; i < 4; ++i) {
            int f4 = t + 256 * i;
            int row = f4 >> 3, c4 = f4 & 7;
            size_t m = (size_t)(b * NSEQ + kc * 128 + row);
            ((float4*)&ks[row][0])[c4] = ((const float4*)(C + m * 768 + 256 + e0))[c4];
            ((float4*)&vs[row][0])[c4] = ((const float4*)(C + m * 768 + 512 + e0))[c4];
        }
        __syncthreads();

        float p[2][4];
        float mloc[2] = {-1e30f, -1e30f};
        #pragma unroll
        for (int j = 0; j < 4; ++j) {
            int kj = tk + 32 * j;
            const float4* krow = (const float4*)&ks[kj][0];
            float s0 = 0.f, s1 = 0.f;
            #pragma unroll
            for (int i = 0; i < 8; ++i) {
                float4 kf = krow[i];
                s0 = dot4acc(s0, qreg[0][i], kf);
                s1 = dot4acc(s1, qreg[1][i], kf);
            }
            p[0][j] = s0 * scale;
            p[1][j] = s1 * scale;
            mloc[0] = fmaxf(mloc[0], p[0][j]);
            mloc[1] = fmaxf(mloc[1], p[1][j]);
        }
        #pragma unroll
        for (int off = 1; off < 32; off <<= 1) {
            mloc[0] = fmaxf(mloc[0], __shfl_xor(mloc[0], off));
            mloc[1] = fmaxf(mloc[1], __shfl_xor(mloc[1], off));
        }
        #pragma unroll
        for (int r = 0; r < 2; ++r) {
            float m_new = fmaxf(m_run[r], mloc[r]);
            float sc = __expf(m_run[r] - m_new);
            m_run[r] = m_new;
            float ls = 0.f;
            #pragma unroll
            for (int j = 0; j < 4; ++j) {
                p[r][j] = __expf(p[r][j] - m_new);
                ls += p[r][j];
            }
            #pragma unroll
            for (int off = 1; off < 32; off <<= 1) ls += __shfl_xor(ls, off);
            l_run[r] = l_run[r] * sc + ls;
            #pragma unroll
            for (int i = 0; i < 8; ++i) {
                pacc[r][i].x *= sc; pacc[r][i].y *= sc;
                pacc[r][i].z *= sc; pacc[r][i].w *= sc;
            }
        }
        #pragma unroll
        for (int j = 0; j < 4; ++j) {
            int kj = tk + 32 * j;
            const float4* vrow = (const float4*)&vs[kj][0];
            float p0 = p[0][j], p1 = p[1][j];
            #pragma unroll
            for (int i = 0; i < 8; ++i) {
                float4 vf = vrow[i];
                pacc[0][i].x = fmaf(p0, vf.x, pacc[0][i].x);
                pacc[0][i].y = fmaf(p0, vf.y, pacc[0][i].y);
                pacc[0][i].z = fmaf(p0, vf.z, pacc[0][i].z);
                pacc[0][i].w = fmaf(p0, vf.w, pacc[0][i].w);
                pacc[1][i].x = fmaf(p1, vf.x, pacc[1][i].x);
                pacc[1][i].y = fmaf(p1, vf.y, pacc[1][i].y);
                pacc[1][i].z = fmaf(p1, vf.z, pacc[1][i].z);
                pacc[1][i].w = fmaf(p1, vf.w, pacc[1][i].w);
            }
        }
    }

    // butterfly-sum across the 32 tk lanes
    #pragma unroll
    for (int r = 0; r < 2; ++r) {
        #pragma unroll
        for (int i = 0; i < 8; ++i) {
            float4 v = pacc[r][i];
            #pragma unroll
            for (int off = 1; off < 32; off <<= 1) {
                v.x += __shfl_xor(v.x, off);
                v.y += __shfl_xor(v.y, off);
                v.z += __shfl_xor(v.z, off);
                v.w += __shfl_xor(v.w, off);
            }
            pacc[r][i] = v;
        }
    }

    // lane tk writes channel tk (static-index select, no scratch)
    #pragma unroll
    for (int r = 0; r < 2; ++r) {
        float val = 0.f;
        #pragma unroll
        for (int i = 0; i < 8; ++i) {
            float4 v = pacc[r][i];
            int cc = tk & 3;
            float comp = (cc == 0) ? v.x : ((cc == 1) ? v.y : ((cc == 2) ? v.z : v.w));
            if ((tk >> 2) == i) val = comp;
        }
        size_t m = (size_t)(b * NSEQ + q0 + 2 * tq + r);
        attnw[m * 256 + e0 + tk] = val / l_run[r];
    }
}

// K3: split-K out-projection partials. grid (16 m, 4 n, 4 ksplit) x 256.
__global__ __launch_bounds__(256, 2) void k_ogemm(
    const float* __restrict__ A, const float* __restrict__ Wo,
    float* __restrict__ yPart)
{
    __shared__ __align__(16) float As[64][68];
    __shared__ __align__(16) float Bs[64][68];
    const int t = threadIdx.x;
    const int tx = t & 15, ty = t >> 4;
    const int m0 = blockIdx.x * 64;
    const int n0 = blockIdx.y * 64;
    const int k0 = blockIdx.z * 64;

    #pragma unroll
    for (int p = 0; p < 4; ++p) {
        int row = p * 16 + ty;
        float4 a = ((const float4*)(A  + (size_t)(m0 + row) * 256 + k0))[tx];
        float4 b = ((const float4*)(Wo + (size_t)(n0 + row) * 256 + k0))[tx];
        int sr = row ^ ((tx & 3) << 2);
        As[tx * 4 + 0][sr] = a.x; As[tx * 4 + 1][sr] = a.y;
        As[tx * 4 + 2][sr] = a.z; As[tx * 4 + 3][sr] = a.w;
        Bs[tx * 4 + 0][sr] = b.x; Bs[tx * 4 + 1][sr] = b.y;
        Bs[tx * 4 + 2][sr] = b.z; Bs[tx * 4 + 3][sr] = b.w;
    }
    __syncthreads();

    float acc[4][4] = {{0.f}};
    #pragma unroll 16
    for (int k = 0; k < 64; ++k) {
        int s = ((k >> 2) & 3) << 2;
        float4 a4 = *(const float4*)&As[k][(ty * 4) ^ s];
        float4 b4 = *(const float4*)&Bs[k][(tx * 4) ^ s];
        acc[0][0] = fmaf(a4.x, b4.x, acc[0][0]);
        acc[0][1] = fmaf(a4.x, b4.y, acc[0][1]);
        acc[0][2] = fmaf(a4.x, b4.z, acc[0][2]);
        acc[0][3] = fmaf(a4.x, b4.w, acc[0][3]);
        acc[1][0] = fmaf(a4.y, b4.x, acc[1][0]);
        acc[1][1] = fmaf(a4.y, b4.y, acc[1][1]);
        acc[1][2] = fmaf(a4.y, b4.z, acc[1][2]);
        acc[1][3] = fmaf(a4.y, b4.w, acc[1][3]);
        acc[2][0] = fmaf(a4.z, b4.x, acc[2][0]);
        acc[2][1] = fmaf(a4.z, b4.y, acc[2][1]);
        acc[2][2] = fmaf(a4.z, b4.z, acc[2][2]);
        acc[2][3] = fmaf(a4.z, b4.w, acc[2][3]);
        acc[3][0] = fmaf(a4.w, b4.x, acc[3][0]);
        acc[3][1] = fmaf(a4.w, b4.y, acc[3][1]);
        acc[3][2] = fmaf(a4.w, b4.z, acc[3][2]);
        acc[3][3] = fmaf(a4.w, b4.w, acc[3][3]);
    }

    float* dst = yPart + (size_t)blockIdx.z * (1024 * 256);
    #pragma unroll
    for (int r = 0; r < 4; ++r) {
        float4 o = make_float4(acc[r][0], acc[r][1], acc[r][2], acc[r][3]);
        *((float4*)(dst + (size_t)(m0 + ty * 4 + r) * 256 + n0 + tx * 4)) = o;
    }
}

// K4: y = x + bo + sum(yPart) ; LN1 ; LN2. grid 256 x 256; 4 rows/block.
__global__ __launch_bounds__(256) void k_lnorm(
    const float* __restrict__ yP, const float* __restrict__ x,
    const float* __restrict__ bo,
    const float* __restrict__ g1, const float* __restrict__ b1,
    const float* __restrict__ g2, const float* __restrict__ b2,
    float* __restrict__ out)
{
    __shared__ float red[4][4][2];
    const int t = threadIdx.x;
    const int r0 = blockIdx.x * 4;
    const int c = t;
    const int wid = t >> 6, lane = t & 63;

    float y[4];
    #pragma unroll
    for (int r = 0; r < 4; ++r) {
        size_t off = (size_t)(r0 + r) * 256 + c;
        y[r] = x[off] + bo[c] + yP[off] + yP[262144 + off]
             + yP[524288 + off] + yP[786432 + off];
    }

    // LN1
    #pragma unroll
    for (int r = 0; r < 4; ++r) {
        float s = y[r], s2 = y[r] * y[r];
        #pragma unroll
        for (int off = 32; off > 0; off >>= 1) {
            s  += __shfl_xor(s, off);
            s2 += __shfl_xor(s2, off);
        }
        if (lane == 0) { red[wid][r][0] = s; red[wid][r][1] = s2; }
    }
    __syncthreads();
    float t1[4];
    #pragma unroll
    for (int r = 0; r < 4; ++r) {
        float s  = red[0][r][0] + red[1][r][0] + red[2][r][0] + red[3][r][0];
        float s2 = red[0][r][1] + red[1][r][1] + red[2][r][1] + red[3][r][1];
        float mu = s * (1.f / 256.f);
        float var = s2 * (1.f / 256.f) - mu * mu;
        float rs = rsqrtf(var + 1e-5f);
        t1[r] = (y[r] - mu) * rs * g1[c] + b1[c];
    }
    __syncthreads();

    // LN2
    #pragma unroll
    for (int r = 0; r < 4; ++r) {
        float s = t1[r], s2 = t1[r] * t1[r];
        #pragma unroll
        for (int off = 32; off > 0; off >>= 1) {
            s  += __shfl_xor(s, off);
            s2 += __shfl_xor(s2, off);
        }
        if (lane == 0) { red[wid][r][0] = s; red[wid][r][1] = s2; }
    }
    __syncthreads();
    #pragma unroll
    for (int r = 0; r < 4; ++r) {
        float s  = red[0][r][0] + red[1][r][0] + red[2][r][0] + red[3][r][0];
        float s2 = red[0][r][1] + red[1][r][1] + red[2][r][1] + red[3][r][1];
        float mu = s * (1.f / 256.f);
        float var = s2 * (1.f / 256.f) - mu * mu;
        float rs = rsqrtf(var + 1e-5f);
        out[(size_t)(r0 + r) * 256 + c] = (t1[r] - mu) * rs * g2[c] + b2[c];
    }
}

extern "C" void kernel_launch(void* const* d_in, const int* in_sizes, int n_in,
                              void* d_out, int out_size, void* d_ws, size_t ws_size,
                              hipStream_t stream)
{
    const float* x  = (const float*)d_in[0];
    const float* Wq = (const float*)d_in[1];
    const float* bq = (const float*)d_in[2];
    const float* Wk = (const float*)d_in[3];
    const float* bk = (const float*)d_in[4];
    const float* Wv = (const float*)d_in[5];
    const float* bv = (const float*)d_in[6];
    const float* Wr = (const float*)d_in[7];
    const float* br = (const float*)d_in[8];
    const float* Wo = (const float*)d_in[9];
    const float* bo = (const float*)d_in[10];
    const float* g1 = (const float*)d_in[11];
    const float* b1 = (const float*)d_in[12];
    const float* g2 = (const float*)d_in[13];
    const float* b2 = (const float*)d_in[14];
    float* out = (float*)d_out;
    float* ws = (float*)d_ws;

    float* C     = ws;                       // 1024*768
    float* attnw = ws + 786432;              // 1024*256
    float* yP    = ws + 1048576;             // 4 * 1024*256
    unsigned* maxEnc = (unsigned*)(ws + 2097152);  // 512

    hipMemsetAsync(maxEnc, 0x00, 512 * sizeof(unsigned), stream);

    k_gemm_proj<<<dim3(16, 16), 256, 0, stream>>>(x, Wq, Wk, Wv, Wr, bq, bk, bv,
                                                  C, maxEnc);
    k_attn<<<dim3(32, 8, 2), 256, 0, stream>>>(C, maxEnc, br, attnw);
    k_ogemm<<<dim3(16, 4, 4), 256, 0, stream>>>(attnw, Wo, yP);
    k_lnorm<<<256, 256, 0, stream>>>(yP, x, bo, g1, b1, g2, b2, out);
}

// Round 6
// 48.976 us; speedup vs baseline: 2.2040x; 1.3799x over previous
//
#include <hip/hip_runtime.h>
#include <hip/hip_bf16.h>
#include <math.h>

#define NSEQ 512
#define EMB 256

typedef __attribute__((ext_vector_type(8))) short bf16x8;
typedef __attribute__((ext_vector_type(4))) float f32x4;

// order-preserving float<->uint encoding for atomic max
__device__ __forceinline__ unsigned fenc(float f) {
    unsigned u = __float_as_uint(f);
    return (u & 0x80000000u) ? ~u : (u | 0x80000000u);
}
__device__ __forceinline__ float fdec(unsigned e) {
    unsigned u = (e & 0x80000000u) ? (e ^ 0x80000000u) : ~e;
    return __uint_as_float(u);
}

__device__ __forceinline__ unsigned short f2bf(float f) {
    unsigned u = __float_as_uint(f);
    unsigned r = (u + 0x7FFFu + ((u >> 16) & 1u)) >> 16;
    return (unsigned short)r;
}

__device__ __forceinline__ float dot4acc(float acc, float4 a, float4 b) {
    acc = fmaf(a.x, b.x, acc);
    acc = fmaf(a.y, b.y, acc);
    acc = fmaf(a.z, b.z, acc);
    acc = fmaf(a.w, b.w, acc);
    return acc;
}

// K0: fp32->bf16 prep. Xb[1024][256]; Wallb[1024][256] = [Wq-Wr; Wk+Wr; Wv; Wr];
// Wob[256][256]. Also inits maxEnc. grid 576 x 256, 1 float4 per thread.
__global__ __launch_bounds__(256) void k_prep(
    const float* __restrict__ X,
    const float* __restrict__ Wq, const float* __restrict__ Wk,
    const float* __restrict__ Wv, const float* __restrict__ Wr,
    const float* __restrict__ Wo,
    unsigned short* __restrict__ Xb, unsigned short* __restrict__ Wallb,
    unsigned short* __restrict__ Wob, unsigned* __restrict__ maxEnc)
{
    const int t = threadIdx.x;
    const int idx4 = blockIdx.x * 256 + t;   // float4 index
    if (blockIdx.x == 0) { maxEnc[t] = 0u; maxEnc[256 + t] = 0u; }
    if (idx4 >= 147456) return;

    float4 v;
    ushort4* dst;
    if (idx4 < 65536) {
        v = ((const float4*)X)[idx4];
        dst = &((ushort4*)Xb)[idx4];
    } else if (idx4 < 131072) {
        int j = idx4 - 65536;
        int row = j >> 6, c4 = j & 63;
        int seg = row >> 8, wr = row & 255;
        size_t off = (size_t)wr * 64 + c4;
        if (seg == 0) {
            float4 a = ((const float4*)Wq)[off], r = ((const float4*)Wr)[off];
            v = make_float4(a.x - r.x, a.y - r.y, a.z - r.z, a.w - r.w);
        } else if (seg == 1) {
            float4 a = ((const float4*)Wk)[off], r = ((const float4*)Wr)[off];
            v = make_float4(a.x + r.x, a.y + r.y, a.z + r.z, a.w + r.w);
        } else if (seg == 2) {
            v = ((const float4*)Wv)[off];
        } else {
            v = ((const float4*)Wr)[off];
        }
        dst = &((ushort4*)Wallb)[j];
    } else {
        int j = idx4 - 131072;
        v = ((const float4*)Wo)[j];
        dst = &((ushort4*)Wob)[j];
    }
    ushort4 o;
    o.x = f2bf(v.x); o.y = f2bf(v.y); o.z = f2bf(v.z); o.w = f2bf(v.w);
    *dst = o;
}

// K1: C[1024][768] = Xb @ Wallb^T (bf16 MFMA, fp32 out, +bias), P-seg -> maxEnc.
// grid (16 m, 16 n) x 256 (4 waves). 64x64 tile, full K=256 in LDS.
// Wave w owns m-rows 16w..16w+15 (1 m-frag x 4 n-frags), 8 K-steps of 32.
__global__ __launch_bounds__(256) void k_gemm_mfma(
    const unsigned short* __restrict__ Xb,
    const unsigned short* __restrict__ Wallb,
    const float* __restrict__ bq, const float* __restrict__ bk,
    const float* __restrict__ bv,
    float* __restrict__ C, unsigned* __restrict__ maxEnc)
{
    __shared__ __align__(16) unsigned short Xs[64 * 264];  // stride 264 bf16 = 528B
    __shared__ __align__(16) unsigned short Ws[64 * 264];
    __shared__ float red[4][64];

    const int t = threadIdx.x;
    const int w = t >> 6, l = t & 63;
    const int ln = l & 15, kg = l >> 4;
    const int m0 = blockIdx.x * 64;
    const int nW = blockIdx.y * 64;           // Wallb row base; C col base if seg<3
    const int seg = blockIdx.y >> 2;          // 0:Q' 1:K' 2:V 3:P

    // stage X-tile and W-tile (64 rows x 256 k, bf16, padded)
    const uint4* Xg = (const uint4*)Xb;       // [1024][32] uint4
    const uint4* Wg = (const uint4*)Wallb;
    #pragma unroll
    for (int i = 0; i < 8; ++i) {
        int idx = i * 256 + t;                // 0..2047
        int row = idx >> 5, c8 = idx & 31;
        *(uint4*)(Xs + row * 264 + c8 * 8) = Xg[(size_t)(m0 + row) * 32 + c8];
        *(uint4*)(Ws + row * 264 + c8 * 8) = Wg[(size_t)(nW + row) * 32 + c8];
    }
    __syncthreads();

    f32x4 acc[4] = {{0.f,0.f,0.f,0.f},{0.f,0.f,0.f,0.f},
                    {0.f,0.f,0.f,0.f},{0.f,0.f,0.f,0.f}};
    const int arow = (w << 4) + ln;
    #pragma unroll
    for (int ks = 0; ks < 8; ++ks) {
        bf16x8 a = *(const bf16x8*)(Xs + arow * 264 + ks * 32 + kg * 8);
        #pragma unroll
        for (int nf = 0; nf < 4; ++nf) {
            bf16x8 b = *(const bf16x8*)(Ws + (nf * 16 + ln) * 264 + ks * 32 + kg * 8);
            acc[nf] = __builtin_amdgcn_mfma_f32_16x16x32_bf16(a, b, acc[nf], 0, 0, 0);
        }
    }

    if (seg < 3) {
        const float* bias = (seg == 0) ? bq : ((seg == 1) ? bk : bv);
        #pragma unroll
        for (int nf = 0; nf < 4; ++nf) {
            float bb = bias[(nW & 255) + nf * 16 + ln];
            #pragma unroll
            for (int r = 0; r < 4; ++r) {
                int row = m0 + w * 16 + kg * 4 + r;
                C[(size_t)row * 768 + nW + nf * 16 + ln] = acc[nf][r] + bb;
            }
        }
    } else {
        // per-(batch,chan) max of P
        #pragma unroll
        for (int nf = 0; nf < 4; ++nf) {
            float mx = fmaxf(fmaxf(acc[nf][0], acc[nf][1]),
                             fmaxf(acc[nf][2], acc[nf][3]));
            mx = fmaxf(mx, __shfl_xor(mx, 16));
            mx = fmaxf(mx, __shfl_xor(mx, 32));
            if (l < 16) red[w][nf * 16 + ln] = mx;
        }
        __syncthreads();
        if (t < 64) {
            float m = fmaxf(fmaxf(red[0][t], red[1][t]),
                            fmaxf(red[2][t], red[3][t]));
            atomicMax(&maxEnc[(m0 >> 9) * 256 + (nW & 255) + t], fenc(m));
        }
    }
}

// K2: attention (fp32, proven round-2/5 structure), output stored as bf16.
__global__ __launch_bounds__(256) void k_attn(
    const float* __restrict__ C,
    const unsigned* __restrict__ maxEnc,
    const float* __restrict__ br, unsigned short* __restrict__ attnb)
{
    __shared__ __align__(16) float ks[128][36];
    __shared__ __align__(16) float vs[128][36];
    __shared__ __align__(16) float qadd[32];

    const int t = threadIdx.x;
    const int q0 = blockIdx.x * 16;
    const int h  = blockIdx.y;
    const int b  = blockIdx.z;
    const int e0 = h * 32;
    const int tq = t >> 5, tk = t & 31;
    const float scale = 0.17677669529663687f;  // 1/sqrt(32)

    if (t < 32)
        qadd[t] = fdec(maxEnc[b * 256 + e0 + t]) + br[e0 + t];
    __syncthreads();

    float4 qreg[2][8];
    #pragma unroll
    for (int r = 0; r < 2; ++r) {
        size_t m = (size_t)(b * NSEQ + q0 + 2 * tq + r);
        const float4* Crow = (const float4*)(C + m * 768 + e0);
        #pragma unroll
        for (int i = 0; i < 8; ++i) {
            float4 qv = Crow[i];
            float4 ad = ((const float4*)qadd)[i];
            qreg[r][i] = make_float4(qv.x + ad.x, qv.y + ad.y, qv.z + ad.z, qv.w + ad.w);
        }
    }

    float m_run[2] = {-1e30f, -1e30f};
    float l_run[2] = {0.f, 0.f};
    float4 pacc[2][8];
    #pragma unroll
    for (int r = 0; r < 2; ++r)
        #pragma unroll
        for (int i = 0; i < 8; ++i)
            pacc[r][i] = make_float4(0.f, 0.f, 0.f, 0.f);

    for (int kc = 0; kc < 4; ++kc) {
        __syncthreads();
        #pragma unroll
        for (int i = 0; i < 4; ++i) {
            int f4 = t + 256 * i;
            int row = f4 >> 3, c4 = f4 & 7;
            size_t m = (size_t)(b * NSEQ + kc * 128 + row);
            ((float4*)&ks[row][0])[c4] = ((const float4*)(C + m * 768 + 256 + e0))[c4];
            ((float4*)&vs[row][0])[c4] = ((const float4*)(C + m * 768 + 512 + e0))[c4];
        }
        __syncthreads();

        float p[2][4];
        float mloc[2] = {-1e30f, -1e30f};
        #pragma unroll
        for (int j = 0; j < 4; ++j) {
            int kj = tk + 32 * j;
            const float4* krow = (const float4*)&ks[kj][0];
            float s0 = 0.f, s1 = 0.f;
            #pragma unroll
            for (int i = 0; i < 8; ++i) {
                float4 kf = krow[i];
                s0 = dot4acc(s0, qreg[0][i], kf);
                s1 = dot4acc(s1, qreg[1][i], kf);
            }
            p[0][j] = s0 * scale;
            p[1][j] = s1 * scale;
            mloc[0] = fmaxf(mloc[0], p[0][j]);
            mloc[1] = fmaxf(mloc[1], p[1][j]);
        }
        #pragma unroll
        for (int off = 1; off < 32; off <<= 1) {
            mloc[0] = fmaxf(mloc[0], __shfl_xor(mloc[0], off));
            mloc[1] = fmaxf(mloc[1], __shfl_xor(mloc[1], off));
        }
        #pragma unroll
        for (int r = 0; r < 2; ++r) {
            float m_new = fmaxf(m_run[r], mloc[r]);
            float sc = __expf(m_run[r] - m_new);
            m_run[r] = m_new;
            float ls = 0.f;
            #pragma unroll
            for (int j = 0; j < 4; ++j) {
                p[r][j] = __expf(p[r][j] - m_new);
                ls += p[r][j];
            }
            #pragma unroll
            for (int off = 1; off < 32; off <<= 1) ls += __shfl_xor(ls, off);
            l_run[r] = l_run[r] * sc + ls;
            #pragma unroll
            for (int i = 0; i < 8; ++i) {
                pacc[r][i].x *= sc; pacc[r][i].y *= sc;
                pacc[r][i].z *= sc; pacc[r][i].w *= sc;
            }
        }
        #pragma unroll
        for (int j = 0; j < 4; ++j) {
            int kj = tk + 32 * j;
            const float4* vrow = (const float4*)&vs[kj][0];
            float p0 = p[0][j], p1 = p[1][j];
            #pragma unroll
            for (int i = 0; i < 8; ++i) {
                float4 vf = vrow[i];
                pacc[0][i].x = fmaf(p0, vf.x, pacc[0][i].x);
                pacc[0][i].y = fmaf(p0, vf.y, pacc[0][i].y);
                pacc[0][i].z = fmaf(p0, vf.z, pacc[0][i].z);
                pacc[0][i].w = fmaf(p0, vf.w, pacc[0][i].w);
                pacc[1][i].x = fmaf(p1, vf.x, pacc[1][i].x);
                pacc[1][i].y = fmaf(p1, vf.y, pacc[1][i].y);
                pacc[1][i].z = fmaf(p1, vf.z, pacc[1][i].z);
                pacc[1][i].w = fmaf(p1, vf.w, pacc[1][i].w);
            }
        }
    }

    #pragma unroll
    for (int r = 0; r < 2; ++r) {
        #pragma unroll
        for (int i = 0; i < 8; ++i) {
            float4 v = pacc[r][i];
            #pragma unroll
            for (int off = 1; off < 32; off <<= 1) {
                v.x += __shfl_xor(v.x, off);
                v.y += __shfl_xor(v.y, off);
                v.z += __shfl_xor(v.z, off);
                v.w += __shfl_xor(v.w, off);
            }
            pacc[r][i] = v;
        }
    }

    #pragma unroll
    for (int r = 0; r < 2; ++r) {
        float val = 0.f;
        #pragma unroll
        for (int i = 0; i < 8; ++i) {
            float4 v = pacc[r][i];
            int cc = tk & 3;
            float comp = (cc == 0) ? v.x : ((cc == 1) ? v.y : ((cc == 2) ? v.z : v.w));
            if ((tk >> 2) == i) val = comp;
        }
        size_t m = (size_t)(b * NSEQ + q0 + 2 * tq + r);
        attnb[m * 256 + e0 + tk] = f2bf(val / l_run[r]);
    }
}

// K3: out-projection, bf16 MFMA, split-K=4. grid (16 m, 4 n, 4 k) x 256.
__global__ __launch_bounds__(256) void k_ogemm_mfma(
    const unsigned short* __restrict__ Ab,   // attnb [1024][256] bf16
    const unsigned short* __restrict__ Wob,  // [256][256] bf16
    float* __restrict__ yPart)
{
    __shared__ __align__(16) unsigned short As_[64 * 72];  // 64 rows x 64k, pad 8
    __shared__ __align__(16) unsigned short Bs_[64 * 72];

    const int t = threadIdx.x;
    const int w = t >> 6, l = t & 63;
    const int ln = l & 15, kg = l >> 4;
    const int m0 = blockIdx.x * 64;
    const int n0 = blockIdx.y * 64;
    const int bz = blockIdx.z;

    const uint4* Ag = (const uint4*)Ab;   // [1024][32]
    const uint4* Wg = (const uint4*)Wob;  // [256][32]
    #pragma unroll
    for (int i = 0; i < 2; ++i) {
        int idx = i * 256 + t;            // 0..511
        int row = idx >> 3, c8 = idx & 7;
        *(uint4*)(As_ + row * 72 + c8 * 8) = Ag[(size_t)(m0 + row) * 32 + bz * 8 + c8];
        *(uint4*)(Bs_ + row * 72 + c8 * 8) = Wg[(size_t)(n0 + row) * 32 + bz * 8 + c8];
    }
    __syncthreads();

    f32x4 acc[4] = {{0.f,0.f,0.f,0.f},{0.f,0.f,0.f,0.f},
                    {0.f,0.f,0.f,0.f},{0.f,0.f,0.f,0.f}};
    const int arow = (w << 4) + ln;
    #pragma unroll
    for (int ks = 0; ks < 2; ++ks) {
        bf16x8 a = *(const bf16x8*)(As_ + arow * 72 + ks * 32 + kg * 8);
        #pragma unroll
        for (int nf = 0; nf < 4; ++nf) {
            bf16x8 b = *(const bf16x8*)(Bs_ + (nf * 16 + ln) * 72 + ks * 32 + kg * 8);
            acc[nf] = __builtin_amdgcn_mfma_f32_16x16x32_bf16(a, b, acc[nf], 0, 0, 0);
        }
    }

    float* dst = yPart + (size_t)bz * (1024 * 256);
    #pragma unroll
    for (int nf = 0; nf < 4; ++nf) {
        #pragma unroll
        for (int r = 0; r < 4; ++r) {
            int row = m0 + w * 16 + kg * 4 + r;
            dst[(size_t)row * 256 + n0 + nf * 16 + ln] = acc[nf][r];
        }
    }
}

// K4: y = x + bo + sum(yPart) ; LN1 ; LN2. grid 256 x 256; 4 rows/block.
__global__ __launch_bounds__(256) void k_lnorm(
    const float* __restrict__ yP, const float* __restrict__ x,
    const float* __restrict__ bo,
    const float* __restrict__ g1, const float* __restrict__ b1,
    const float* __restrict__ g2, const float* __restrict__ b2,
    float* __restrict__ out)
{
    __shared__ float red[4][4][2];
    const int t = threadIdx.x;
    const int r0 = blockIdx.x * 4;
    const int c = t;
    const int wid = t >> 6, lane = t & 63;

    float y[4];
    #pragma unroll
    for (int r = 0; r < 4; ++r) {
        size_t off = (size_t)(r0 + r) * 256 + c;
        y[r] = x[off] + bo[c] + yP[off] + yP[262144 + off]
             + yP[524288 + off] + yP[786432 + off];
    }

    // LN1
    #pragma unroll
    for (int r = 0; r < 4; ++r) {
        float s = y[r], s2 = y[r] * y[r];
        #pragma unroll
        for (int off = 32; off > 0; off >>= 1) {
            s  += __shfl_xor(s, off);
            s2 += __shfl_xor(s2, off);
        }
        if (lane == 0) { red[wid][r][0] = s; red[wid][r][1] = s2; }
    }
    __syncthreads();
    float t1[4];
    #pragma unroll
    for (int r = 0; r < 4; ++r) {
        float s  = red[0][r][0] + red[1][r][0] + red[2][r][0] + red[3][r][0];
        float s2 = red[0][r][1] + red[1][r][1] + red[2][r][1] + red[3][r][1];
        float mu = s * (1.f / 256.f);
        float var = s2 * (1.f / 256.f) - mu * mu;
        float rs = rsqrtf(var + 1e-5f);
        t1[r] = (y[r] - mu) * rs * g1[c] + b1[c];
    }
    __syncthreads();

    // LN2
    #pragma unroll
    for (int r = 0; r < 4; ++r) {
        float s = t1[r], s2 = t1[r] * t1[r];
        #pragma unroll
        for (int off = 32; off > 0; off >>= 1) {
            s  += __shfl_xor(s, off);
            s2 += __shfl_xor(s2, off);
        }
        if (lane == 0) { red[wid][r][0] = s; red[wid][r][1] = s2; }
    }
    __syncthreads();
    #pragma unroll
    for (int r = 0; r < 4; ++r) {
        float s  = red[0][r][0] + red[1][r][0] + red[2][r][0] + red[3][r][0];
        float s2 = red[0][r][1] + red[1][r][1] + red[2][r][1] + red[3][r][1];
        float mu = s * (1.f / 256.f);
        float var = s2 * (1.f / 256.f) - mu * mu;
        float rs = rsqrtf(var + 1e-5f);
        out[(size_t)(r0 + r) * 256 + c] = (t1[r] - mu) * rs * g2[c] + b2[c];
    }
}

extern "C" void kernel_launch(void* const* d_in, const int* in_sizes, int n_in,
                              void* d_out, int out_size, void* d_ws, size_t ws_size,
                              hipStream_t stream)
{
    const float* x  = (const float*)d_in[0];
    const float* Wq = (const float*)d_in[1];
    const float* bq = (const float*)d_in[2];
    const float* Wk = (const float*)d_in[3];
    const float* bk = (const float*)d_in[4];
    const float* Wv = (const float*)d_in[5];
    const float* bv = (const float*)d_in[6];
    const float* Wr = (const float*)d_in[7];
    const float* br = (const float*)d_in[8];
    const float* Wo = (const float*)d_in[9];
    const float* bo = (const float*)d_in[10];
    const float* g1 = (const float*)d_in[11];
    const float* b1 = (const float*)d_in[12];
    const float* g2 = (const float*)d_in[13];
    const float* b2 = (const float*)d_in[14];
    float* out = (float*)d_out;
    float* ws = (float*)d_ws;

    // workspace layout (float offsets)
    float* C      = ws;                                   // 1024*768
    float* yP     = ws + 786432;                          // 4 * 1024*256
    unsigned short* attnb = (unsigned short*)(ws + 1835008);  // 1024*256 bf16
    unsigned short* Xb    = (unsigned short*)(ws + 1966080);  // 1024*256 bf16
    unsigned short* Wallb = (unsigned short*)(ws + 2097152);  // 1024*256 bf16
    unsigned short* Wob   = (unsigned short*)(ws + 2228224);  // 256*256 bf16
    unsigned* maxEnc      = (unsigned*)(ws + 2260992);        // 512

    k_prep<<<576, 256, 0, stream>>>(x, Wq, Wk, Wv, Wr, Wo, Xb, Wallb, Wob, maxEnc);
    k_gemm_mfma<<<dim3(16, 16), 256, 0, stream>>>(Xb, Wallb, bq, bk, bv, C, maxEnc);
    k_attn<<<dim3(32, 8, 2), 256, 0, stream>>>(C, maxEnc, br, attnb);
    k_ogemm_mfma<<<dim3(16, 4, 4), 256, 0, stream>>>(attnb, Wob, yP);
    k_lnorm<<<256, 256, 0, stream>>>(yP, x, bo, g1, b1, g2, b2, out);
}

// Round 7
// 31.923 us; speedup vs baseline: 3.3813x; 1.5342x over previous
//
#include <hip/hip_runtime.h>
#include <hip/hip_bf16.h>
#include <math.h>

#define NSEQ 512
#define EMB 256

typedef __attribute__((ext_vector_type(8))) short bf16x8;
typedef __attribute__((ext_vector_type(4))) float f32x4;

// order-preserving float<->uint encoding for atomic max
__device__ __forceinline__ unsigned fenc(float f) {
    unsigned u = __float_as_uint(f);
    return (u & 0x80000000u) ? ~u : (u | 0x80000000u);
}
__device__ __forceinline__ float fdec(unsigned e) {
    unsigned u = (e & 0x80000000u) ? (e ^ 0x80000000u) : ~e;
    return __uint_as_float(u);
}

__device__ __forceinline__ unsigned short f2bf(float f) {
    unsigned u = __float_as_uint(f);
    unsigned r = (u + 0x7FFFu + ((u >> 16) & 1u)) >> 16;
    return (unsigned short)r;
}
__device__ __forceinline__ float bf2f(unsigned short s) {
    return __uint_as_float(((unsigned)s) << 16);
}

// K0: fp32->bf16 prep. Xb[1024][256]; Wallb[1024][256] = [Wq-Wr; Wk+Wr; Wv; Wr];
// Wob[256][256]. Also inits maxEnc. grid 576 x 256, 1 float4 per thread.
__global__ __launch_bounds__(256) void k_prep(
    const float* __restrict__ X,
    const float* __restrict__ Wq, const float* __restrict__ Wk,
    const float* __restrict__ Wv, const float* __restrict__ Wr,
    const float* __restrict__ Wo,
    unsigned short* __restrict__ Xb, unsigned short* __restrict__ Wallb,
    unsigned short* __restrict__ Wob, unsigned* __restrict__ maxEnc)
{
    const int t = threadIdx.x;
    const int idx4 = blockIdx.x * 256 + t;   // float4 index
    if (blockIdx.x == 0) { maxEnc[t] = 0u; maxEnc[256 + t] = 0u; }
    if (idx4 >= 147456) return;

    float4 v;
    ushort4* dst;
    if (idx4 < 65536) {
        v = ((const float4*)X)[idx4];
        dst = &((ushort4*)Xb)[idx4];
    } else if (idx4 < 131072) {
        int j = idx4 - 65536;
        int row = j >> 6, c4 = j & 63;
        int seg = row >> 8, wr = row & 255;
        size_t off = (size_t)wr * 64 + c4;
        if (seg == 0) {
            float4 a = ((const float4*)Wq)[off], r = ((const float4*)Wr)[off];
            v = make_float4(a.x - r.x, a.y - r.y, a.z - r.z, a.w - r.w);
        } else if (seg == 1) {
            float4 a = ((const float4*)Wk)[off], r = ((const float4*)Wr)[off];
            v = make_float4(a.x + r.x, a.y + r.y, a.z + r.z, a.w + r.w);
        } else if (seg == 2) {
            v = ((const float4*)Wv)[off];
        } else {
            v = ((const float4*)Wr)[off];
        }
        dst = &((ushort4*)Wallb)[j];
    } else {
        int j = idx4 - 131072;
        v = ((const float4*)Wo)[j];
        dst = &((ushort4*)Wob)[j];
    }
    ushort4 o;
    o.x = f2bf(v.x); o.y = f2bf(v.y); o.z = f2bf(v.z); o.w = f2bf(v.w);
    *dst = o;
}

// K1: projections via bf16 MFMA. Outputs:
//   seg0: Qb[1024][256] bf16 = X(Wq-Wr)^T + bq   (qadd added later in attn)
//   seg1: Kb[1024][256] bf16 = X(Wk+Wr)^T        (ALL K-side bias cancels in softmax)
//   seg2: Vtb[16 bh][32][512] bf16 = (XWv^T + bv) transposed per (b,h)
//   seg3: P = XWr^T -> per-(batch,chan) max -> maxEnc (atomics)
// grid (16 m, 16 n) x 256 (4 waves). 64x64 tile, full K=256 in LDS.
__global__ __launch_bounds__(256) void k_gemm_mfma(
    const unsigned short* __restrict__ Xb,
    const unsigned short* __restrict__ Wallb,
    const float* __restrict__ bq, const float* __restrict__ bv,
    unsigned short* __restrict__ Qb, unsigned short* __restrict__ Kb,
    unsigned short* __restrict__ Vtb, unsigned* __restrict__ maxEnc)
{
    __shared__ __align__(16) unsigned short Xs[64 * 264];  // stride 264 bf16 = 528B
    __shared__ __align__(16) unsigned short Ws[64 * 264];
    __shared__ float red[4][64];

    const int t = threadIdx.x;
    const int w = t >> 6, l = t & 63;
    const int ln = l & 15, kg = l >> 4;
    const int m0 = blockIdx.x * 64;
    const int nW = blockIdx.y * 64;           // Wallb row base
    const int seg = blockIdx.y >> 2;          // 0:Q' 1:K' 2:V 3:P

    const uint4* Xg = (const uint4*)Xb;       // [1024][32] uint4
    const uint4* Wg = (const uint4*)Wallb;
    #pragma unroll
    for (int i = 0; i < 8; ++i) {
        int idx = i * 256 + t;                // 0..2047
        int row = idx >> 5, c8 = idx & 31;
        *(uint4*)(Xs + row * 264 + c8 * 8) = Xg[(size_t)(m0 + row) * 32 + c8];
        *(uint4*)(Ws + row * 264 + c8 * 8) = Wg[(size_t)(nW + row) * 32 + c8];
    }
    __syncthreads();

    f32x4 acc[4] = {{0.f,0.f,0.f,0.f},{0.f,0.f,0.f,0.f},
                    {0.f,0.f,0.f,0.f},{0.f,0.f,0.f,0.f}};
    const int arow = (w << 4) + ln;
    #pragma unroll
    for (int ks = 0; ks < 8; ++ks) {
        bf16x8 a = *(const bf16x8*)(Xs + arow * 264 + ks * 32 + kg * 8);
        #pragma unroll
        for (int nf = 0; nf < 4; ++nf) {
            bf16x8 b = *(const bf16x8*)(Ws + (nf * 16 + ln) * 264 + ks * 32 + kg * 8);
            acc[nf] = __builtin_amdgcn_mfma_f32_16x16x32_bf16(a, b, acc[nf], 0, 0, 0);
        }
    }

    if (seg == 0) {
        #pragma unroll
        for (int nf = 0; nf < 4; ++nf) {
            int c = (nW & 255) + nf * 16 + ln;
            float bb = bq[c];
            #pragma unroll
            for (int r = 0; r < 4; ++r) {
                int row = m0 + w * 16 + kg * 4 + r;
                Qb[(size_t)row * 256 + c] = f2bf(acc[nf][r] + bb);
            }
        }
    } else if (seg == 1) {
        #pragma unroll
        for (int nf = 0; nf < 4; ++nf) {
            int c = (nW & 255) + nf * 16 + ln;
            #pragma unroll
            for (int r = 0; r < 4; ++r) {
                int row = m0 + w * 16 + kg * 4 + r;
                Kb[(size_t)row * 256 + c] = f2bf(acc[nf][r]);
            }
        }
    } else if (seg == 2) {
        #pragma unroll
        for (int nf = 0; nf < 4; ++nf) {
            int c = (nW & 255) + nf * 16 + ln;   // global channel 0..255
            int h = c >> 5, d = c & 31;
            float bb = bv[c];
            #pragma unroll
            for (int r = 0; r < 4; ++r) {
                int row = m0 + w * 16 + kg * 4 + r;
                int b = row >> 9, ml = row & 511;
                Vtb[((size_t)(b * 8 + h) * 32 + d) * 512 + ml] = f2bf(acc[nf][r] + bb);
            }
        }
    } else {
        #pragma unroll
        for (int nf = 0; nf < 4; ++nf) {
            float mx = fmaxf(fmaxf(acc[nf][0], acc[nf][1]),
                             fmaxf(acc[nf][2], acc[nf][3]));
            mx = fmaxf(mx, __shfl_xor(mx, 16));
            mx = fmaxf(mx, __shfl_xor(mx, 32));
            if (l < 16) red[w][nf * 16 + ln] = mx;
        }
        __syncthreads();
        if (t < 64) {
            float m = fmaxf(fmaxf(red[0][t], red[1][t]),
                            fmaxf(red[2][t], red[3][t]));
            atomicMax(&maxEnc[(m0 >> 9) * 256 + (nW & 255) + t], fenc(m));
        }
    }
}

// K2: MFMA flash attention. grid (32 q-tiles of 16, 8 h, 2 b) x 256 (4 waves).
// Wave w handles keys w*128..w*128+127 (single-pass softmax, no rescale).
// QK^T and PV via mfma_16x16x32_bf16; K/Vt frags direct from global (L2).
// Wave-private P round-trip via padded LDS; one cross-wave combine at end.
__global__ __launch_bounds__(256) void k_attn_mfma(
    const unsigned short* __restrict__ Qb,   // [1024][256] bf16
    const unsigned short* __restrict__ Kb,   // [1024][256] bf16
    const unsigned short* __restrict__ Vtb,  // [16][32][512] bf16
    const unsigned* __restrict__ maxEnc,
    const float* __restrict__ br,
    unsigned short* __restrict__ attnb)      // [1024][256] bf16
{
    __shared__ __align__(16) unsigned short Plds[4][16][136];
    __shared__ float Olds[4][16][33];
    __shared__ float mlds[4][16], llds[4][16];
    __shared__ float scl[4][16], Li[16];

    const int t = threadIdx.x;
    const int w = t >> 6, l = t & 63;
    const int ln = l & 15, kg = l >> 4;
    const int q0 = blockIdx.x * 16;
    const int h = blockIdx.y, b = blockIdx.z;
    const int e0 = h * 32;
    const int bh = b * 8 + h;
    const float scale = 0.17677669529663687f;  // 1/sqrt(32)

    // a-frag: Qr = (Qb + maxP + br) * scale, re-rounded to bf16
    bf16x8 af;
    {
        size_t qrow = (size_t)(b * NSEQ + q0 + ln) * 256 + e0 + kg * 8;
        bf16x8 qa = *(const bf16x8*)(Qb + qrow);
        #pragma unroll
        for (int j = 0; j < 8; ++j) {
            int d = kg * 8 + j;
            float qv = bf2f((unsigned short)qa[j]);
            float ad = fdec(maxEnc[b * 256 + e0 + d]) + br[e0 + d];
            af[j] = (short)f2bf((qv + ad) * scale);
        }
    }

    // QK^T: 8 key-frags of 16 (this wave's 128 keys)
    const int key0 = w * 128;
    f32x4 sc[8];
    #pragma unroll
    for (int kf = 0; kf < 8; ++kf) {
        size_t krow = (size_t)(b * NSEQ + key0 + kf * 16 + ln) * 256 + e0 + kg * 8;
        bf16x8 bfr = *(const bf16x8*)(Kb + krow);
        f32x4 z = {0.f, 0.f, 0.f, 0.f};
        sc[kf] = __builtin_amdgcn_mfma_f32_16x16x32_bf16(af, bfr, z, 0, 0, 0);
    }

    // single-pass softmax over this wave's 128 keys; lane owns q = kg*4+r
    float m_[4], l_[4];
    #pragma unroll
    for (int r = 0; r < 4; ++r) {
        float mx = sc[0][r];
        #pragma unroll
        for (int kf = 1; kf < 8; ++kf) mx = fmaxf(mx, sc[kf][r]);
        #pragma unroll
        for (int off = 1; off < 16; off <<= 1) mx = fmaxf(mx, __shfl_xor(mx, off));
        m_[r] = mx;
        float s = 0.f;
        #pragma unroll
        for (int kf = 0; kf < 8; ++kf) {
            float p = __expf(sc[kf][r] - mx);
            sc[kf][r] = p;
            s += p;
        }
        #pragma unroll
        for (int off = 1; off < 16; off <<= 1) s += __shfl_xor(s, off);
        l_[r] = s;
    }

    // P -> LDS (bf16), wave-private
    #pragma unroll
    for (int kf = 0; kf < 8; ++kf)
        #pragma unroll
        for (int r = 0; r < 4; ++r)
            Plds[w][kg * 4 + r][kf * 16 + ln] = f2bf(sc[kf][r]);

    // PV: O[16 q][32 d], a = P frags from LDS, b = Vt frags from global
    f32x4 o[2] = {{0.f,0.f,0.f,0.f},{0.f,0.f,0.f,0.f}};
    #pragma unroll
    for (int ks = 0; ks < 4; ++ks) {
        bf16x8 pf = *(const bf16x8*)&Plds[w][ln][ks * 32 + kg * 8];
        #pragma unroll
        for (int df = 0; df < 2; ++df) {
            size_t vrow = ((size_t)bh * 32 + df * 16 + ln) * 512 + key0 + ks * 32 + kg * 8;
            bf16x8 vf = *(const bf16x8*)(Vtb + vrow);
            o[df] = __builtin_amdgcn_mfma_f32_16x16x32_bf16(pf, vf, o[df], 0, 0, 0);
        }
    }

    // write partials
    if (ln == 0) {
        #pragma unroll
        for (int r = 0; r < 4; ++r) {
            mlds[w][kg * 4 + r] = m_[r];
            llds[w][kg * 4 + r] = l_[r];
        }
    }
    #pragma unroll
    for (int df = 0; df < 2; ++df)
        #pragma unroll
        for (int r = 0; r < 4; ++r)
            Olds[w][kg * 4 + r][df * 16 + ln] = o[df][r];
    __syncthreads();

    // combine scales per q (threads 0..15)
    if (t < 16) {
        float M = fmaxf(fmaxf(mlds[0][t], mlds[1][t]),
                        fmaxf(mlds[2][t], mlds[3][t]));
        float L = 0.f;
        #pragma unroll
        for (int wv = 0; wv < 4; ++wv) {
            float s = __expf(mlds[wv][t] - M);
            scl[wv][t] = s;
            L += s * llds[wv][t];
        }
        Li[t] = 1.f / L;
    }
    __syncthreads();

    // combine elements: 512 outputs, 2 per thread
    #pragma unroll
    for (int i = 0; i < 2; ++i) {
        int idx = t + 256 * i;
        int q = idx >> 5, d = idx & 31;
        float acc = 0.f;
        #pragma unroll
        for (int wv = 0; wv < 4; ++wv)
            acc += scl[wv][q] * Olds[wv][q][d];
        attnb[(size_t)(b * NSEQ + q0 + q) * 256 + e0 + d] = f2bf(acc * Li[q]);
    }
}

// K3: out-projection, bf16 MFMA, split-K=4. grid (16 m, 4 n, 4 k) x 256.
__global__ __launch_bounds__(256) void k_ogemm_mfma(
    const unsigned short* __restrict__ Ab,   // attnb [1024][256] bf16
    const unsigned short* __restrict__ Wob,  // [256][256] bf16
    float* __restrict__ yPart)
{
    __shared__ __align__(16) unsigned short As_[64 * 72];
    __shared__ __align__(16) unsigned short Bs_[64 * 72];

    const int t = threadIdx.x;
    const int w = t >> 6, l = t & 63;
    const int ln = l & 15, kg = l >> 4;
    const int m0 = blockIdx.x * 64;
    const int n0 = blockIdx.y * 64;
    const int bz = blockIdx.z;

    const uint4* Ag = (const uint4*)Ab;   // [1024][32]
    const uint4* Wg = (const uint4*)Wob;  // [256][32]
    #pragma unroll
    for (int i = 0; i < 2; ++i) {
        int idx = i * 256 + t;            // 0..511
        int row = idx >> 3, c8 = idx & 7;
        *(uint4*)(As_ + row * 72 + c8 * 8) = Ag[(size_t)(m0 + row) * 32 + bz * 8 + c8];
        *(uint4*)(Bs_ + row * 72 + c8 * 8) = Wg[(size_t)(n0 + row) * 32 + bz * 8 + c8];
    }
    __syncthreads();

    f32x4 acc[4] = {{0.f,0.f,0.f,0.f},{0.f,0.f,0.f,0.f},
                    {0.f,0.f,0.f,0.f},{0.f,0.f,0.f,0.f}};
    const int arow = (w << 4) + ln;
    #pragma unroll
    for (int ks = 0; ks < 2; ++ks) {
        bf16x8 a = *(const bf16x8*)(As_ + arow * 72 + ks * 32 + kg * 8);
        #pragma unroll
        for (int nf = 0; nf < 4; ++nf) {
            bf16x8 b = *(const bf16x8*)(Bs_ + (nf * 16 + ln) * 72 + ks * 32 + kg * 8);
            acc[nf] = __builtin_amdgcn_mfma_f32_16x16x32_bf16(a, b, acc[nf], 0, 0, 0);
        }
    }

    float* dst = yPart + (size_t)bz * (1024 * 256);
    #pragma unroll
    for (int nf = 0; nf < 4; ++nf) {
        #pragma unroll
        for (int r = 0; r < 4; ++r) {
            int row = m0 + w * 16 + kg * 4 + r;
            dst[(size_t)row * 256 + n0 + nf * 16 + ln] = acc[nf][r];
        }
    }
}

// K4: y = x + bo + sum(yPart) ; LN1 ; LN2. grid 256 x 256; 4 rows/block.
__global__ __launch_bounds__(256) void k_lnorm(
    const float* __restrict__ yP, const float* __restrict__ x,
    const float* __restrict__ bo,
    const float* __restrict__ g1, const float* __restrict__ b1,
    const float* __restrict__ g2, const float* __restrict__ b2,
    float* __restrict__ out)
{
    __shared__ float red[4][4][2];
    const int t = threadIdx.x;
    const int r0 = blockIdx.x * 4;
    const int c = t;
    const int wid = t >> 6, lane = t & 63;

    float y[4];
    #pragma unroll
    for (int r = 0; r < 4; ++r) {
        size_t off = (size_t)(r0 + r) * 256 + c;
        y[r] = x[off] + bo[c] + yP[off] + yP[262144 + off]
             + yP[524288 + off] + yP[786432 + off];
    }

    // LN1
    #pragma unroll
    for (int r = 0; r < 4; ++r) {
        float s = y[r], s2 = y[r] * y[r];
        #pragma unroll
        for (int off = 32; off > 0; off >>= 1) {
            s  += __shfl_xor(s, off);
            s2 += __shfl_xor(s2, off);
        }
        if (lane == 0) { red[wid][r][0] = s; red[wid][r][1] = s2; }
    }
    __syncthreads();
    float t1[4];
    #pragma unroll
    for (int r = 0; r < 4; ++r) {
        float s  = red[0][r][0] + red[1][r][0] + red[2][r][0] + red[3][r][0];
        float s2 = red[0][r][1] + red[1][r][1] + red[2][r][1] + red[3][r][1];
        float mu = s * (1.f / 256.f);
        float var = s2 * (1.f / 256.f) - mu * mu;
        float rs = rsqrtf(var + 1e-5f);
        t1[r] = (y[r] - mu) * rs * g1[c] + b1[c];
    }
    __syncthreads();

    // LN2
    #pragma unroll
    for (int r = 0; r < 4; ++r) {
        float s = t1[r], s2 = t1[r] * t1[r];
        #pragma unroll
        for (int off = 32; off > 0; off >>= 1) {
            s  += __shfl_xor(s, off);
            s2 += __shfl_xor(s2, off);
        }
        if (lane == 0) { red[wid][r][0] = s; red[wid][r][1] = s2; }
    }
    __syncthreads();
    #pragma unroll
    for (int r = 0; r < 4; ++r) {
        float s  = red[0][r][0] + red[1][r][0] + red[2][r][0] + red[3][r][0];
        float s2 = red[0][r][1] + red[1][r][1] + red[2][r][1] + red[3][r][1];
        float mu = s * (1.f / 256.f);
        float var = s2 * (1.f / 256.f) - mu * mu;
        float rs = rsqrtf(var + 1e-5f);
        out[(size_t)(r0 + r) * 256 + c] = (t1[r] - mu) * rs * g2[c] + b2[c];
    }
}

extern "C" void kernel_launch(void* const* d_in, const int* in_sizes, int n_in,
                              void* d_out, int out_size, void* d_ws, size_t ws_size,
                              hipStream_t stream)
{
    const float* x  = (const float*)d_in[0];
    const float* Wq = (const float*)d_in[1];
    const float* bq = (const float*)d_in[2];
    const float* Wk = (const float*)d_in[3];
    const float* bk = (const float*)d_in[4];   // cancels in softmax (unused)
    const float* Wv = (const float*)d_in[5];
    const float* bv = (const float*)d_in[6];
    const float* Wr = (const float*)d_in[7];
    const float* br = (const float*)d_in[8];
    const float* Wo = (const float*)d_in[9];
    const float* bo = (const float*)d_in[10];
    const float* g1 = (const float*)d_in[11];
    const float* b1 = (const float*)d_in[12];
    const float* g2 = (const float*)d_in[13];
    const float* b2 = (const float*)d_in[14];
    float* out = (float*)d_out;
    float* ws = (float*)d_ws;
    (void)bk;

    // workspace layout (float offsets)
    float* yP = ws;                                            // 4*1024*256
    unsigned short* Xb    = (unsigned short*)(ws + 1048576);   // 1024*256 bf16
    unsigned short* Wallb = (unsigned short*)(ws + 1179648);   // 1024*256 bf16
    unsigned short* Wob   = (unsigned short*)(ws + 1310720);   // 256*256 bf16
    unsigned short* Qb    = (unsigned short*)(ws + 1343488);   // 1024*256 bf16
    unsigned short* Kb    = (unsigned short*)(ws + 1474560);   // 1024*256 bf16
    unsigned short* Vtb   = (unsigned short*)(ws + 1605632);   // 16*32*512 bf16
    unsigned short* attnb = (unsigned short*)(ws + 1736704);   // 1024*256 bf16
    unsigned* maxEnc      = (unsigned*)(ws + 1867776);         // 512

    k_prep<<<576, 256, 0, stream>>>(x, Wq, Wk, Wv, Wr, Wo, Xb, Wallb, Wob, maxEnc);
    k_gemm_mfma<<<dim3(16, 16), 256, 0, stream>>>(Xb, Wallb, bq, bv,
                                                  Qb, Kb, Vtb, maxEnc);
    k_attn_mfma<<<dim3(32, 8, 2), 256, 0, stream>>>(Qb, Kb, Vtb, maxEnc, br, attnb);
    k_ogemm_mfma<<<dim3(16, 4, 4), 256, 0, stream>>>(attnb, Wob, yP);
    k_lnorm<<<256, 256, 0, stream>>>(yP, x, bo, g1, b1, g2, b2, out);
}